// Round 10
// baseline (320.930 us; speedup 1.0000x reference)
//
#include <hip/hip_runtime.h>

#define N_NODES 100000
#define N_EDGES 1000000
#define N_GRAPHS 512
#define N_CLS 10
#define BN_EPS 1e-5f

#define SCAN_NB 200    // 200 * 512 = 102400 >= N_NODES
#define NTILES2 3125   // 100000 / 32 exactly (32-node tiles, no tail)

typedef _Float16 half8 __attribute__((ext_vector_type(8)));
typedef _Float16 half4v __attribute__((ext_vector_type(4)));
typedef float floatx4 __attribute__((ext_vector_type(4)));

// ---------------------------------------------------------------- prep (R10: histogram only)
// rank round-trip removed: plain atomicAdd histogram (no return, no 4MB store);
// x->fp16 convert moved into fill (overlaps fill's latency-bound scatter).
__global__ __launch_bounds__(256) void prep_kernel(
    const int* __restrict__ batch, const int* __restrict__ dstI,
    int* __restrict__ deg,
    const float* __restrict__ w0a, const float* __restrict__ b0a,
    const float* __restrict__ g0, const float* __restrict__ be0,
    const float* __restrict__ m0, const float* __restrict__ v0,
    const float* __restrict__ w0b,
    const float* __restrict__ w1a, const float* __restrict__ b1a,
    const float* __restrict__ g1, const float* __restrict__ be1,
    const float* __restrict__ m1, const float* __restrict__ v1,
    const float* __restrict__ w1b,
    int* __restrict__ gstart,
    _Float16* __restrict__ wHi, _Float16* __restrict__ wLo,
    float* __restrict__ b1p0, float* __restrict__ b1p1) {
    const int gid = blockIdx.x * 256 + threadIdx.x;

    if (gid < N_EDGES)  // histogram (no rank)
        atomicAdd(&deg[dstI[gid]], 1);

    if (gid <= N_NODES) {  // graph boundaries from sorted batch
        int bcur = (gid < N_NODES) ? batch[gid] : N_GRAPHS;
        int bprev = (gid > 0) ? batch[gid - 1] : -1;
        for (int g = bprev + 1; g <= bcur; ++g) gstart[g] = gid;
    }

    if (gid < 16384) {  // W frag pack: [mat(4)][k0(2)][c(4)][lane(64)][jj(8)]
        const int e = gid & 4095, mat = gid >> 12;
        const int jj = e & 7, lane = (e >> 3) & 63, c = (e >> 9) & 3, k0 = (e >> 11) & 1;
        const int k = k0 * 32 + (lane >> 4) * 8 + jj;
        const int col = c * 16 + (lane & 15);
        float val;
        if (mat == 0)      val = w0a[k * 64 + col] * (rsqrtf(v0[col] + BN_EPS) * g0[col]);
        else if (mat == 1) val = w0b[k * 64 + col];
        else if (mat == 2) val = w1a[k * 64 + col] * (rsqrtf(v1[col] + BN_EPS) * g1[col]);
        else               val = w1b[k * 64 + col];
        _Float16 hi = (_Float16)val;
        wHi[gid] = hi;
        wLo[gid] = (_Float16)(val - (float)hi);
    }

    if (gid >= 16384 && gid < 16512) {  // BN-folded biases
        int t = gid - 16384;
        if (t < 64) {
            float s = rsqrtf(v0[t] + BN_EPS) * g0[t];
            b1p0[t] = (b0a[t] - m0[t]) * s + be0[t];
        } else {
            t -= 64;
            float s = rsqrtf(v1[t] + BN_EPS) * g1[t];
            b1p1[t] = (b1a[t] - m1[t]) * s + be1[t];
        }
    }
}

// ---------------------------------------------------------------- 2-kernel scan
__global__ __launch_bounds__(256) void scanA_kernel(const int* __restrict__ deg,
                                                    int* __restrict__ bsum) {
    __shared__ int sh[256];
    const int base = blockIdx.x * 512;
    const int t = threadIdx.x;
    int a = 0, b = 0;
    if (base + t < N_NODES) a = deg[base + t];
    if (base + 256 + t < N_NODES) b = deg[base + 256 + t];
    sh[t] = a + b;
    __syncthreads();
#pragma unroll
    for (int off = 128; off > 0; off >>= 1) {
        if (t < off) sh[t] += sh[t + off];
        __syncthreads();
    }
    if (t == 0) bsum[blockIdx.x] = sh[0];
}

// scanC re-derives its own block offset from bsum; writes rowptr AND the fill
// cursor copy (fill consumes cursor with atomics, rowptr stays clean for conv).
__global__ __launch_bounds__(256) void scanC_kernel(const int* __restrict__ deg,
                                                    const int* __restrict__ bsum,
                                                    int* __restrict__ rowptr,
                                                    int* __restrict__ cursor) {
    __shared__ int sh[256];
    __shared__ int sboff[256];
    const int base = blockIdx.x * 512;
    const int t = threadIdx.x;

    const int bv = (t < SCAN_NB) ? bsum[t] : 0;
    sboff[t] = bv;

    const int i0 = base + 2 * t, i1 = i0 + 1;
    const int d0 = (i0 < N_NODES) ? deg[i0] : 0;
    const int d1 = (i1 < N_NODES) ? deg[i1] : 0;
    const int p = d0 + d1;
    sh[t] = p;
    __syncthreads();
#pragma unroll
    for (int off = 1; off < 256; off <<= 1) {
        int u = (t >= off) ? sh[t - off] : 0;
        int ub = (t >= off) ? sboff[t - off] : 0;
        __syncthreads();
        sh[t] += u;
        sboff[t] += ub;
        __syncthreads();
    }
    const int myoff = (blockIdx.x == 0) ? 0 : sboff[blockIdx.x - 1];
    const int excl = myoff + sh[t] - p;
    if (i0 < N_NODES) { rowptr[i0] = excl;      cursor[i0] = excl; }
    if (i1 < N_NODES) { rowptr[i1] = excl + d0; cursor[i1] = excl + d0; }
    if (blockIdx.x == 0 && t == 0) rowptr[N_NODES] = N_EDGES;
}

// ---------------------------------------------------------------- fill + x->fp16 convert
// Slot derived on the fly from the cursor copy (order within a dst bucket is
// arbitrary — aggregation is a sum). The convert loop (38MB streaming) overlaps
// the latency/atomic-bound scatter.
__global__ __launch_bounds__(256) void fill_kernel(const float* __restrict__ x,
                                                   _Float16* __restrict__ xh,
                                                   const int* __restrict__ srcI,
                                                   const int* __restrict__ dstI,
                                                   int* __restrict__ cursor,
                                                   int* __restrict__ sortedSrc) {
    const int gid = blockIdx.x * 256 + threadIdx.x;

    if (gid < 1600000) {  // x -> fp16 (6.4M elems as float4 -> half4)
        float4 v = ((const float4*)x)[gid];
        half4v h = {(_Float16)v.x, (_Float16)v.y, (_Float16)v.z, (_Float16)v.w};
        ((half4v*)xh)[gid] = h;
    }

    if (gid < N_EDGES) {
        const int pos = atomicAdd(&cursor[dstI[gid]], 1);
        sortedSrc[pos] = srcI[gid];
    }
}

// swizzled half-index into a [16][64] fp16 plane: row*64 + (col ^ ((row&7)<<3)).
// 16-B-granular XOR keeps half4v/half8 alignment; spreads the stride-128B rows
// across 8 bank slots -> reads 2-way (free), writes conflict-free.
__device__ __forceinline__ int swz(int row, int col) {
    return row * 64 + (col ^ ((row & 7) << 3));
}

// ---------------------------------------------------------------- pipelined gather stages
// IDX stage: ONE coalesced load per 4-node group — lane l fetches the src id of
// (node l>>4, edge-slot l&15), i.e. 4 runs of <=16 consecutive ints of sortedSrc.
__device__ __forceinline__ void idx_stage(const int* __restrict__ srcList, int rpv,
                                          int mq, int nodeSel, int slotSel, int& idxOwn) {
    const int rr0 = __shfl(rpv, mq * 4 + nodeSel, 64);
    const int rr1 = __shfl(rpv, mq * 4 + nodeSel + 1, 64);
    const int c = rr1 - rr0;
    const int e0 = (c > 0) ? min(slotSel, c - 1) : 0;
    int pos = rr0 + e0;
    pos = min(pos, N_EDGES - 1);  // cnt==0 tail nodes: stay in-bounds (value unused)
    idxOwn = srcList[pos];
}

// ROWS stage: broadcast indices via __shfl, issue 4 self + up-to-16 row loads for
// group mq. Issued one full consume-phase before use (FIFO-vmcnt safe).
__device__ __forceinline__ void rows_stage(const _Float16* __restrict__ in, int rpv,
                                           int mq, int strip0, int eoff, int lf,
                                           int idxOwn, half4v (&vT)[4][4], half4v (&sS)[4]) {
    const int m0 = mq * 4;
#pragma unroll
    for (int i = 0; i < 4; ++i) {
        sS[i] = (half4v){0, 0, 0, 0};
        if (eoff == 0)
            sS[i] = *(const half4v*)(in + (size_t)(strip0 + m0 + i) * 64 + lf * 4);
    }
#pragma unroll
    for (int i = 0; i < 4; ++i) {
        const int rr0 = __builtin_amdgcn_readlane(rpv, m0 + i);
        const int rr1 = __builtin_amdgcn_readlane(rpv, m0 + i + 1);
        const int cI = rr1 - rr0;
        const int g = (min(cI, 16) + 3) >> 2;
#pragma unroll
        for (int k = 0; k < 4; ++k) {
            vT[i][k] = (half4v){0, 0, 0, 0};
            if (k < g) {
                const int id = __shfl(idxOwn, i * 16 + 4 * k + eoff, 64);
                vT[i][k] = *(const half4v*)(in + (size_t)id * 64 + lf * 4);
            }
        }
    }
}

// CONSUME stage: accumulate prefetched rows, rare >16-degree spill, self, reduce,
// write hi/lo fp16 planes to swizzled LDS.
__device__ __forceinline__ void consume_stage(const _Float16* __restrict__ in,
                                              const int* __restrict__ srcList, int rpv,
                                              int mq, int eoff, int lf, int j,
                                              const half4v (&vT)[4][4], const half4v (&sS)[4],
                                              _Float16* aggH, _Float16* aggL) {
    const int m0 = mq * 4;
#pragma unroll
    for (int i = 0; i < 4; ++i) {
        const int rr0 = __builtin_amdgcn_readlane(rpv, m0 + i);
        const int rr1 = __builtin_amdgcn_readlane(rpv, m0 + i + 1);
        const int cI = rr1 - rr0;
        float aR[4] = {0.f, 0.f, 0.f, 0.f};
#pragma unroll
        for (int k = 0; k < 4; ++k) {
            if (4 * k + eoff < cI) {
                aR[0] += (float)vT[i][k].x; aR[1] += (float)vT[i][k].y;
                aR[2] += (float)vT[i][k].z; aR[3] += (float)vT[i][k].w;
            }
        }
        for (int eb = 16; eb < cI; eb += 16) {
#pragma unroll
            for (int k = 0; k < 4; ++k) {
                const int e_ = eb + 4 * k + eoff;
                if (e_ < cI) {
                    const int id = srcList[rr0 + e_];
                    half4v t = *(const half4v*)(in + (size_t)id * 64 + lf * 4);
                    aR[0] += (float)t.x; aR[1] += (float)t.y;
                    aR[2] += (float)t.z; aR[3] += (float)t.w;
                }
            }
        }
        if (eoff == 0) {
            aR[0] += (float)sS[i].x; aR[1] += (float)sS[i].y;
            aR[2] += (float)sS[i].z; aR[3] += (float)sS[i].w;
        }
#pragma unroll
        for (int q = 0; q < 4; ++q) {
            aR[q] += __shfl_xor(aR[q], 16, 64);
            aR[q] += __shfl_xor(aR[q], 32, 64);
        }
        if (j < 16) {
            half4v hi, lo;
#pragma unroll
            for (int q = 0; q < 4; ++q) {
                hi[q] = (_Float16)aR[q];
                lo[q] = (_Float16)(aR[q] - (float)hi[q]);
            }
            const int idx = swz(m0 + i, 4 * j);
            *(half4v*)(aggH + idx) = hi;
            *(half4v*)(aggL + idx) = lo;
        }
    }
}

#define SBAR() __builtin_amdgcn_sched_barrier(0)

// ---------------------------------------------------------------- fused conv (MFMA, fp16)
// R8-exact (best measured): 32-node tiles, 2 waves/block, grid 3125, LDS 8192 B.
template <int POOL>
__global__ __launch_bounds__(128, 2) void conv_mfma(
    const _Float16* __restrict__ in, const int* __restrict__ rowptr,
    const int* __restrict__ srcList,
    const _Float16* __restrict__ wH1, const _Float16* __restrict__ wL1,
    const _Float16* __restrict__ wH2, const _Float16* __restrict__ wL2,
    const float* __restrict__ b1, const float* __restrict__ b2,
    _Float16* __restrict__ out, const int* __restrict__ batch,
    float* __restrict__ pooled) {
    // per-wave 4096 B: aggH fp16 [16][64] swizzled (2048 B) | aggL fp16 (2048 B)
    __shared__ __align__(16) unsigned char scratch[2][4096];

    const int tid = threadIdx.x;
    const int j = tid & 63, wv = tid >> 6;   // 2 waves
    const int eoff = j >> 4;
    const int lf = j & 15;
    const int base = blockIdx.x * 32;
    const int strip0 = base + wv * 16;       // always < N_NODES (3125*32 = 100000 exact)

    int bb = 0;
    if (POOL) bb = batch[strip0 + min(j, 15)];  // batch ids in registers (lanes 0..15)

    const int rpv = rowptr[strip0 + min(j, 16)];

    _Float16* aggH = (_Float16*)scratch[wv];
    _Float16* aggL = aggH + 1024;

    // ---- pipelined aggregation: I0 I1 | R0 I2 | R1 C0 | I3 R2 C1 | R3 C2 | C3
    {
        int idxA, idxB, idxC;
        half4v vA[4][4], vB[4][4], sA[4], sB[4];

        idx_stage(srcList, rpv, 0, eoff, lf, idxA);
        idx_stage(srcList, rpv, 1, eoff, lf, idxB);
        SBAR();
        rows_stage(in, rpv, 0, strip0, eoff, lf, idxA, vA, sA);
        SBAR();
        idx_stage(srcList, rpv, 2, eoff, lf, idxC);
        SBAR();
        rows_stage(in, rpv, 1, strip0, eoff, lf, idxB, vB, sB);
        SBAR();
        consume_stage(in, srcList, rpv, 0, eoff, lf, j, vA, sA, aggH, aggL);
        SBAR();
        idx_stage(srcList, rpv, 3, eoff, lf, idxA);
        SBAR();
        rows_stage(in, rpv, 2, strip0, eoff, lf, idxC, vA, sA);
        SBAR();
        consume_stage(in, srcList, rpv, 1, eoff, lf, j, vB, sB, aggH, aggL);
        SBAR();
        rows_stage(in, rpv, 3, strip0, eoff, lf, idxA, vB, sB);
        SBAR();
        consume_stage(in, srcList, rpv, 2, eoff, lf, j, vA, sA, aggH, aggL);
        SBAR();
        consume_stage(in, srcList, rpv, 3, eoff, lf, j, vB, sB, aggH, aggL);
    }

    const int l15 = j & 15, quad = j >> 4;
    const floatx4 vzero = {0.f, 0.f, 0.f, 0.f};

    floatx4 acc[4] = {vzero, vzero, vzero, vzero};
    {
#pragma unroll
        for (int k0 = 0; k0 < 2; ++k0) {
            const int aidx = swz(l15, quad * 8 + k0 * 32);
            half8 aH = *(const half8*)(aggH + aidx);
            half8 aL = *(const half8*)(aggL + aidx);
#pragma unroll
            for (int c = 0; c < 4; ++c) {
                const int fo = ((k0 * 4 + c) * 64 + j) * 8;
                half8 bH = *(const half8*)(wH1 + fo);
                half8 bL = *(const half8*)(wL1 + fo);
                acc[c] = __builtin_amdgcn_mfma_f32_16x16x32_f16(aH, bH, acc[c], 0, 0, 0);
                acc[c] = __builtin_amdgcn_mfma_f32_16x16x32_f16(aL, bH, acc[c], 0, 0, 0);
                acc[c] = __builtin_amdgcn_mfma_f32_16x16x32_f16(aH, bL, acc[c], 0, 0, 0);
            }
        }
    }
    _Float16* hH = aggH;
    _Float16* hL = aggL;
#pragma unroll
    for (int c = 0; c < 4; ++c) {
        const float bv = b1[c * 16 + l15];
#pragma unroll
        for (int r = 0; r < 4; ++r) {
            const int idx = swz(quad * 4 + r, c * 16 + l15);
            float v = acc[c][r] + bv;
            v = fmaxf(v, 0.f);
            const _Float16 hi = (_Float16)v;
            hH[idx] = hi;
            hL[idx] = (_Float16)(v - (float)hi);
        }
    }

    floatx4 acc2[4] = {vzero, vzero, vzero, vzero};
    {
#pragma unroll
        for (int k0 = 0; k0 < 2; ++k0) {
            const int aidx = swz(l15, quad * 8 + k0 * 32);
            half8 aH = *(const half8*)(hH + aidx);
            half8 aL = *(const half8*)(hL + aidx);
#pragma unroll
            for (int c = 0; c < 4; ++c) {
                const int fo = ((k0 * 4 + c) * 64 + j) * 8;
                half8 bH = *(const half8*)(wH2 + fo);
                half8 bL = *(const half8*)(wL2 + fo);
                acc2[c] = __builtin_amdgcn_mfma_f32_16x16x32_f16(aH, bH, acc2[c], 0, 0, 0);
                acc2[c] = __builtin_amdgcn_mfma_f32_16x16x32_f16(aL, bH, acc2[c], 0, 0, 0);
                acc2[c] = __builtin_amdgcn_mfma_f32_16x16x32_f16(aH, bL, acc2[c], 0, 0, 0);
            }
        }
    }

    if (!POOL) {
#pragma unroll
        for (int c = 0; c < 4; ++c) {
            const float bv = b2[c * 16 + l15];
#pragma unroll
            for (int r = 0; r < 4; ++r) {
                const int node = strip0 + quad * 4 + r;
                out[(size_t)node * 64 + c * 16 + l15] =
                    (_Float16)fmaxf(acc2[c][r] + bv, 0.f);
            }
        }
    } else {
        // oT fp32 [16][64] overlays the (dead) agg planes: exactly 4096 B.
        float* oT = (float*)scratch[wv];
#pragma unroll
        for (int c = 0; c < 4; ++c) {
            const float bv = b2[c * 16 + l15];
#pragma unroll
            for (int r = 0; r < 4; ++r)
                oT[(quad * 4 + r) * 64 + c * 16 + l15] = acc2[c][r] + bv;
        }
        __builtin_amdgcn_s_waitcnt(0);  // drain LDS writes (wave-local scratch)
        // run-merged per-wave pool: batch ids wave-uniform via readlane,
        // partial sums straight to global atomics (no cross-wave LDS needed).
        int curB = -1;
        float accv = 0.f;
#pragma unroll
        for (int r = 0; r < 16; ++r) {
            const int b = __builtin_amdgcn_readlane(bb, r);  // wave-uniform
            const float v = oT[r * 64 + j];
            if (b != curB) {
                if (curB >= 0) atomicAdd(&pooled[curB * 64 + j], accv);
                curB = b;
                accv = v;
            } else {
                accv += v;
            }
        }
        atomicAdd(&pooled[curB * 64 + j], accv);
    }
}

// ---------------------------------------------------------------- classifier
__global__ __launch_bounds__(64) void classifier_kernel(const float* __restrict__ pooled,
                                                        const int* __restrict__ gstart,
                                                        const float* __restrict__ wc,
                                                        const float* __restrict__ bc,
                                                        float* __restrict__ out) {
    const int g = blockIdx.x;
    const int j = threadIdx.x;
    const float c = fmaxf((float)(gstart[g + 1] - gstart[g]), 1.f);
    const float mean = pooled[g * 64 + j] / c;
#pragma unroll
    for (int cc = 0; cc < N_CLS; ++cc) {
        float p = mean * wc[j * N_CLS + cc];
#pragma unroll
        for (int off = 32; off > 0; off >>= 1) p += __shfl_down(p, off, 64);
        if (j == 0) out[g * N_CLS + cc] = p + bc[cc];
    }
}

// ---------------------------------------------------------------- launch

extern "C" void kernel_launch(void* const* d_in, const int* in_sizes, int n_in,
                              void* d_out, int out_size, void* d_ws, size_t ws_size,
                              hipStream_t stream) {
    const float* x   = (const float*)d_in[0];
    const int*   ei  = (const int*)d_in[1];
    const int* batch = (const int*)d_in[2];
    const float* w0a = (const float*)d_in[3];
    const float* b0a = (const float*)d_in[4];
    const float* g0  = (const float*)d_in[5];
    const float* be0 = (const float*)d_in[6];
    const float* m0  = (const float*)d_in[7];
    const float* v0  = (const float*)d_in[8];
    const float* w0b = (const float*)d_in[9];
    const float* b0b = (const float*)d_in[10];
    const float* w1a = (const float*)d_in[11];
    const float* b1a = (const float*)d_in[12];
    const float* g1  = (const float*)d_in[13];
    const float* be1 = (const float*)d_in[14];
    const float* m1  = (const float*)d_in[15];
    const float* v1  = (const float*)d_in[16];
    const float* w1b = (const float*)d_in[17];
    const float* b1b = (const float*)d_in[18];
    const float* wc  = (const float*)d_in[19];
    const float* bc  = (const float*)d_in[20];
    float* out = (float*)d_out;

    const int* srcI = ei;
    const int* dstI = ei + N_EDGES;

    // workspace layout, offsets in 4-byte units
    int* ws = (int*)d_ws;
    int*      deg       = ws;                              // 100000
    int*      bsum      = ws + 100000;                     // 200
    float*    pooled    = (float*)(ws + 100404);           // 32768
    int*      rowptr    = ws + 133172;                     // 100001
    int*      cursor    = ws + 233176;                     // 100000 (was rank)
    int*      sortedSrc = ws + 1233176;                    // 1000000
    _Float16* xh        = (_Float16*)(ws + 2233176);       // 6400000 halves
    _Float16* h1        = (_Float16*)(ws + 5433176);       // 6400000 halves
    float*    b1p0      = (float*)(ws + 8633176);          // 64
    float*    b1p1      = (float*)(ws + 8633240);          // 64
    int*      gstart    = ws + 8633304;                    // 513
    _Float16* wHi       = (_Float16*)(ws + 8633820);       // 16384 halves
    _Float16* wLo       = (_Float16*)(ws + 8642012);       // 16384 halves

    (void)hipMemsetAsync((void*)deg, 0, 133172 * sizeof(int), stream);

    // prep: histogram + W pack + gstart (convert moved to fill)
    prep_kernel<<<3907, 256, 0, stream>>>(batch, dstI, deg,
                                          w0a, b0a, g0, be0, m0, v0, w0b,
                                          w1a, b1a, g1, be1, m1, v1, w1b,
                                          gstart, wHi, wLo, b1p0, b1p1);

    scanA_kernel<<<SCAN_NB, 256, 0, stream>>>(deg, bsum);
    scanC_kernel<<<SCAN_NB, 256, 0, stream>>>(deg, bsum, rowptr, cursor);

    // fill (cursor-atomic slot) + x->fp16 convert (overlapped)
    fill_kernel<<<6250, 256, 0, stream>>>(x, xh, srcI, dstI, cursor, sortedSrc);

    // conv0: h1 = relu(mlp0(x + gather(x)))   [fp16 features]
    conv_mfma<0><<<NTILES2, 128, 0, stream>>>(xh, rowptr, sortedSrc,
                                              wHi, wLo, wHi + 4096, wLo + 4096,
                                              b1p0, b0b, h1, nullptr, nullptr);

    // conv1: pooled += mlp1(h1 + gather(h1))
    conv_mfma<1><<<NTILES2, 128, 0, stream>>>(h1, rowptr, sortedSrc,
                                              wHi + 8192, wLo + 8192, wHi + 12288, wLo + 12288,
                                              b1p1, b1b, nullptr, batch, pooled);

    classifier_kernel<<<N_GRAPHS, 64, 0, stream>>>(pooled, gstart, wc, bc, out);
}

// Round 11
// 272.987 us; speedup vs baseline: 1.1756x; 1.1756x over previous
//
#include <hip/hip_runtime.h>

#define N_NODES 100000
#define N_EDGES 1000000
#define N_GRAPHS 512
#define N_CLS 10
#define BN_EPS 1e-5f

#define NTILES2 3125   // 100000 / 32 exactly (32-node tiles, no tail)
#define SLOT_CAP 20    // per-node slot capacity; deg>20 goes to overflow list
#define OVF_CAP 50000  // overflow pairs capacity (expected ~350 for Poisson(10))

typedef _Float16 half8 __attribute__((ext_vector_type(8)));
typedef _Float16 half4v __attribute__((ext_vector_type(4)));
typedef float floatx4 __attribute__((ext_vector_type(4)));

// ---------------------------------------------------------------- prep (R11)
// Single pass builds the adjacency directly: rank = atomicAdd(deg); rank<20 ->
// slots[dst*20+rank]=src, else -> overflow (dst,src) list. No scan, no fill.
// Convert + gstart + W-pack unchanged; the scatter overlaps the 38MB stream.
__global__ __launch_bounds__(256) void prep_kernel(
    const float* __restrict__ x, _Float16* __restrict__ xh,
    const int* __restrict__ batch, const int* __restrict__ srcI,
    const int* __restrict__ dstI,
    int* __restrict__ deg, int* __restrict__ slots,
    int* __restrict__ novf, int2* __restrict__ ovf,
    const float* __restrict__ w0a, const float* __restrict__ b0a,
    const float* __restrict__ g0, const float* __restrict__ be0,
    const float* __restrict__ m0, const float* __restrict__ v0,
    const float* __restrict__ w0b,
    const float* __restrict__ w1a, const float* __restrict__ b1a,
    const float* __restrict__ g1, const float* __restrict__ be1,
    const float* __restrict__ m1, const float* __restrict__ v1,
    const float* __restrict__ w1b,
    int* __restrict__ gstart,
    _Float16* __restrict__ wHi, _Float16* __restrict__ wLo,
    float* __restrict__ b1p0, float* __restrict__ b1p1) {
    const int gid = blockIdx.x * 256 + threadIdx.x;

    if (gid < 1600000) {  // x -> fp16 (6.4M elems as float4 -> half4)
        float4 v = ((const float4*)x)[gid];
        half4v h = {(_Float16)v.x, (_Float16)v.y, (_Float16)v.z, (_Float16)v.w};
        ((half4v*)xh)[gid] = h;
    }

    if (gid < N_EDGES) {  // adjacency build: one atomic pass total
        const int dst = dstI[gid];
        const int rank = atomicAdd(&deg[dst], 1);
        if (rank < SLOT_CAP) {
            slots[(size_t)dst * SLOT_CAP + rank] = srcI[gid];
        } else {
            const int o = atomicAdd(novf, 1);
            if (o < OVF_CAP) ovf[o] = make_int2(dst, srcI[gid]);
        }
    }

    if (gid <= N_NODES) {  // graph boundaries from sorted batch
        int bcur = (gid < N_NODES) ? batch[gid] : N_GRAPHS;
        int bprev = (gid > 0) ? batch[gid - 1] : -1;
        for (int g = bprev + 1; g <= bcur; ++g) gstart[g] = gid;
    }

    if (gid < 16384) {  // W frag pack: [mat(4)][k0(2)][c(4)][lane(64)][jj(8)]
        const int e = gid & 4095, mat = gid >> 12;
        const int jj = e & 7, lane = (e >> 3) & 63, c = (e >> 9) & 3, k0 = (e >> 11) & 1;
        const int k = k0 * 32 + (lane >> 4) * 8 + jj;
        const int col = c * 16 + (lane & 15);
        float val;
        if (mat == 0)      val = w0a[k * 64 + col] * (rsqrtf(v0[col] + BN_EPS) * g0[col]);
        else if (mat == 1) val = w0b[k * 64 + col];
        else if (mat == 2) val = w1a[k * 64 + col] * (rsqrtf(v1[col] + BN_EPS) * g1[col]);
        else               val = w1b[k * 64 + col];
        _Float16 hi = (_Float16)val;
        wHi[gid] = hi;
        wLo[gid] = (_Float16)(val - (float)hi);
    }

    if (gid >= 16384 && gid < 16512) {  // BN-folded biases
        int t = gid - 16384;
        if (t < 64) {
            float s = rsqrtf(v0[t] + BN_EPS) * g0[t];
            b1p0[t] = (b0a[t] - m0[t]) * s + be0[t];
        } else {
            t -= 64;
            float s = rsqrtf(v1[t] + BN_EPS) * g1[t];
            b1p1[t] = (b1a[t] - m1[t]) * s + be1[t];
        }
    }
}

// swizzled half-index into a [16][64] fp16 plane: row*64 + (col ^ ((row&7)<<3)).
__device__ __forceinline__ int swz(int row, int col) {
    return row * 64 + (col ^ ((row & 7) << 3));
}

// ---------------------------------------------------------------- pipelined gather stages
// IDX stage: lane l fetches the src id of (node mq*4 + (l>>4), slot l&15) —
// 4 runs of <=16 consecutive ints of the node's slot segment.
__device__ __forceinline__ void idx_stage(const int* __restrict__ slots, int cntv,
                                          int strip0, int mq, int nodeSel, int slotSel,
                                          int& idxOwn) {
    const int cnt = __shfl(cntv, mq * 4 + nodeSel, 64);
    const int node = strip0 + mq * 4 + nodeSel;
    const int e0 = (cnt > 0) ? min(slotSel, cnt - 1) : 0;
    idxOwn = slots[(size_t)node * SLOT_CAP + e0];
}

// ROWS stage: broadcast indices via __shfl, issue 4 self + up-to-16 row loads for
// group mq. Issued one full consume-phase before use (FIFO-vmcnt safe).
__device__ __forceinline__ void rows_stage(const _Float16* __restrict__ in, int cntv,
                                           int mq, int strip0, int eoff, int lf,
                                           int idxOwn, half4v (&vT)[4][4], half4v (&sS)[4]) {
    const int m0 = mq * 4;
#pragma unroll
    for (int i = 0; i < 4; ++i) {
        sS[i] = (half4v){0, 0, 0, 0};
        if (eoff == 0)
            sS[i] = *(const half4v*)(in + (size_t)(strip0 + m0 + i) * 64 + lf * 4);
    }
#pragma unroll
    for (int i = 0; i < 4; ++i) {
        const int cI = __builtin_amdgcn_readlane(cntv, m0 + i);
        const int g = (min(cI, 16) + 3) >> 2;
#pragma unroll
        for (int k = 0; k < 4; ++k) {
            vT[i][k] = (half4v){0, 0, 0, 0};
            if (k < g) {
                const int id = __shfl(idxOwn, i * 16 + 4 * k + eoff, 64);
                vT[i][k] = *(const half4v*)(in + (size_t)id * 64 + lf * 4);
            }
        }
    }
}

// CONSUME stage: accumulate prefetched rows, slots 16..19 spill, self, reduce,
// write hi/lo fp16 planes to swizzled LDS. (deg>20 handled by overflow pass.)
__device__ __forceinline__ void consume_stage(const _Float16* __restrict__ in,
                                              const int* __restrict__ slots, int cntv,
                                              int strip0, int mq, int eoff, int lf, int j,
                                              const half4v (&vT)[4][4], const half4v (&sS)[4],
                                              _Float16* aggH, _Float16* aggL) {
    const int m0 = mq * 4;
#pragma unroll
    for (int i = 0; i < 4; ++i) {
        const int cI = __builtin_amdgcn_readlane(cntv, m0 + i);
        const int node = strip0 + m0 + i;
        float aR[4] = {0.f, 0.f, 0.f, 0.f};
#pragma unroll
        for (int k = 0; k < 4; ++k) {
            if (4 * k + eoff < cI) {
                aR[0] += (float)vT[i][k].x; aR[1] += (float)vT[i][k].y;
                aR[2] += (float)vT[i][k].z; aR[3] += (float)vT[i][k].w;
            }
        }
        if (cI > 16) {  // slots 16..19 (one 4-edge batch, lanes eoff 0..3 k=0)
            const int e_ = 16 + eoff;
            if (e_ < cI && e_ < SLOT_CAP) {
                const int id = slots[(size_t)node * SLOT_CAP + e_];
                half4v t = *(const half4v*)(in + (size_t)id * 64 + lf * 4);
                aR[0] += (float)t.x; aR[1] += (float)t.y;
                aR[2] += (float)t.z; aR[3] += (float)t.w;
            }
        }
        if (eoff == 0) {
            aR[0] += (float)sS[i].x; aR[1] += (float)sS[i].y;
            aR[2] += (float)sS[i].z; aR[3] += (float)sS[i].w;
        }
#pragma unroll
        for (int q = 0; q < 4; ++q) {
            aR[q] += __shfl_xor(aR[q], 16, 64);
            aR[q] += __shfl_xor(aR[q], 32, 64);
        }
        if (j < 16) {
            half4v hi, lo;
#pragma unroll
            for (int q = 0; q < 4; ++q) {
                hi[q] = (_Float16)aR[q];
                lo[q] = (_Float16)(aR[q] - (float)hi[q]);
            }
            const int idx = swz(m0 + i, 4 * j);
            *(half4v*)(aggH + idx) = hi;
            *(half4v*)(aggL + idx) = lo;
        }
    }
}

#define SBAR() __builtin_amdgcn_sched_barrier(0)

// ---------------------------------------------------------------- fused conv (MFMA, fp16)
// R11: slot-table adjacency (no rowptr/sortedSrc). Otherwise R8-exact: 32-node
// tiles, 2 waves/block, grid 3125, LDS 8192 B, hi/lo fp16 MFMA epilogue.
template <int POOL>
__global__ __launch_bounds__(128, 2) void conv_mfma(
    const _Float16* __restrict__ in, const int* __restrict__ deg,
    const int* __restrict__ slots,
    const int* __restrict__ novf, const int2* __restrict__ ovf,
    const _Float16* __restrict__ wH1, const _Float16* __restrict__ wL1,
    const _Float16* __restrict__ wH2, const _Float16* __restrict__ wL2,
    const float* __restrict__ b1, const float* __restrict__ b2,
    _Float16* __restrict__ out, const int* __restrict__ batch,
    float* __restrict__ pooled) {
    // per-wave 4096 B: aggH fp16 [16][64] swizzled (2048 B) | aggL fp16 (2048 B)
    __shared__ __align__(16) unsigned char scratch[2][4096];

    const int tid = threadIdx.x;
    const int j = tid & 63, wv = tid >> 6;   // 2 waves
    const int eoff = j >> 4;
    const int lf = j & 15;
    const int base = blockIdx.x * 32;
    const int strip0 = base + wv * 16;       // always < N_NODES (3125*32 = 100000 exact)

    int bb = 0;
    if (POOL) bb = batch[strip0 + min(j, 15)];  // batch ids in registers (lanes 0..15)

    const int cntv = deg[strip0 + min(j, 15)];  // per-node counts (lanes 0..15)

    _Float16* aggH = (_Float16*)scratch[wv];
    _Float16* aggL = aggH + 1024;

    // ---- pipelined aggregation: I0 I1 | R0 I2 | R1 C0 | I3 R2 C1 | R3 C2 | C3
    {
        int idxA, idxB, idxC;
        half4v vA[4][4], vB[4][4], sA[4], sB[4];

        idx_stage(slots, cntv, strip0, 0, eoff, lf, idxA);
        idx_stage(slots, cntv, strip0, 1, eoff, lf, idxB);
        SBAR();
        rows_stage(in, cntv, 0, strip0, eoff, lf, idxA, vA, sA);
        SBAR();
        idx_stage(slots, cntv, strip0, 2, eoff, lf, idxC);
        SBAR();
        rows_stage(in, cntv, 1, strip0, eoff, lf, idxB, vB, sB);
        SBAR();
        consume_stage(in, slots, cntv, strip0, 0, eoff, lf, j, vA, sA, aggH, aggL);
        SBAR();
        idx_stage(slots, cntv, strip0, 3, eoff, lf, idxA);
        SBAR();
        rows_stage(in, cntv, 2, strip0, eoff, lf, idxC, vA, sA);
        SBAR();
        consume_stage(in, slots, cntv, strip0, 1, eoff, lf, j, vB, sB, aggH, aggL);
        SBAR();
        rows_stage(in, cntv, 3, strip0, eoff, lf, idxA, vB, sB);
        SBAR();
        consume_stage(in, slots, cntv, strip0, 2, eoff, lf, j, vA, sA, aggH, aggL);
        SBAR();
        consume_stage(in, slots, cntv, strip0, 3, eoff, lf, j, vB, sB, aggH, aggL);
    }

    // ---- overflow pass (rare: nodes with deg > SLOT_CAP). 64-lane parallel
    // scan of the (dst,src) list; per match, lanes 0..15 RMW the hi/lo agg row.
    if (__any((j < 16) && (cntv > SLOT_CAP))) {
        const int nov = min(*novf, OVF_CAP);
        for (int e0 = 0; e0 < nov; e0 += 64) {
            const int e = e0 + j;
            int d = -1, s = 0;
            if (e < nov) { const int2 p = ovf[e]; d = p.x; s = p.y; }
            const int rel = d - strip0;
            unsigned long long m = __ballot((rel >= 0) && (rel < 16));
            while (m) {
                const int l = (int)__ffsll(m) - 1;
                m &= m - 1;
                const int ii = __shfl(rel, l, 64);
                const int ss = __shfl(s, l, 64);
                if (j < 16) {
                    const half4v t = *(const half4v*)(in + (size_t)ss * 64 + j * 4);
                    const int idx = swz(ii, 4 * j);
                    half4v hv = *(half4v*)(aggH + idx);
                    half4v lv = *(half4v*)(aggL + idx);
                    half4v nh, nl;
#pragma unroll
                    for (int q = 0; q < 4; ++q) {
                        const float f = (float)hv[q] + (float)lv[q] + (float)t[q];
                        nh[q] = (_Float16)f;
                        nl[q] = (_Float16)(f - (float)nh[q]);
                    }
                    *(half4v*)(aggH + idx) = nh;
                    *(half4v*)(aggL + idx) = nl;
                }
            }
        }
    }

    const int l15 = j & 15, quad = j >> 4;
    const floatx4 vzero = {0.f, 0.f, 0.f, 0.f};

    floatx4 acc[4] = {vzero, vzero, vzero, vzero};
    {
#pragma unroll
        for (int k0 = 0; k0 < 2; ++k0) {
            const int aidx = swz(l15, quad * 8 + k0 * 32);
            half8 aH = *(const half8*)(aggH + aidx);
            half8 aL = *(const half8*)(aggL + aidx);
#pragma unroll
            for (int c = 0; c < 4; ++c) {
                const int fo = ((k0 * 4 + c) * 64 + j) * 8;
                half8 bH = *(const half8*)(wH1 + fo);
                half8 bL = *(const half8*)(wL1 + fo);
                acc[c] = __builtin_amdgcn_mfma_f32_16x16x32_f16(aH, bH, acc[c], 0, 0, 0);
                acc[c] = __builtin_amdgcn_mfma_f32_16x16x32_f16(aL, bH, acc[c], 0, 0, 0);
                acc[c] = __builtin_amdgcn_mfma_f32_16x16x32_f16(aH, bL, acc[c], 0, 0, 0);
            }
        }
    }
    _Float16* hH = aggH;
    _Float16* hL = aggL;
#pragma unroll
    for (int c = 0; c < 4; ++c) {
        const float bv = b1[c * 16 + l15];
#pragma unroll
        for (int r = 0; r < 4; ++r) {
            const int idx = swz(quad * 4 + r, c * 16 + l15);
            float v = acc[c][r] + bv;
            v = fmaxf(v, 0.f);
            const _Float16 hi = (_Float16)v;
            hH[idx] = hi;
            hL[idx] = (_Float16)(v - (float)hi);
        }
    }

    floatx4 acc2[4] = {vzero, vzero, vzero, vzero};
    {
#pragma unroll
        for (int k0 = 0; k0 < 2; ++k0) {
            const int aidx = swz(l15, quad * 8 + k0 * 32);
            half8 aH = *(const half8*)(hH + aidx);
            half8 aL = *(const half8*)(hL + aidx);
#pragma unroll
            for (int c = 0; c < 4; ++c) {
                const int fo = ((k0 * 4 + c) * 64 + j) * 8;
                half8 bH = *(const half8*)(wH2 + fo);
                half8 bL = *(const half8*)(wL2 + fo);
                acc2[c] = __builtin_amdgcn_mfma_f32_16x16x32_f16(aH, bH, acc2[c], 0, 0, 0);
                acc2[c] = __builtin_amdgcn_mfma_f32_16x16x32_f16(aL, bH, acc2[c], 0, 0, 0);
                acc2[c] = __builtin_amdgcn_mfma_f32_16x16x32_f16(aH, bL, acc2[c], 0, 0, 0);
            }
        }
    }

    if (!POOL) {
#pragma unroll
        for (int c = 0; c < 4; ++c) {
            const float bv = b2[c * 16 + l15];
#pragma unroll
            for (int r = 0; r < 4; ++r) {
                const int node = strip0 + quad * 4 + r;
                out[(size_t)node * 64 + c * 16 + l15] =
                    (_Float16)fmaxf(acc2[c][r] + bv, 0.f);
            }
        }
    } else {
        // oT fp32 [16][64] overlays the (dead) agg planes: exactly 4096 B.
        float* oT = (float*)scratch[wv];
#pragma unroll
        for (int c = 0; c < 4; ++c) {
            const float bv = b2[c * 16 + l15];
#pragma unroll
            for (int r = 0; r < 4; ++r)
                oT[(quad * 4 + r) * 64 + c * 16 + l15] = acc2[c][r] + bv;
        }
        __builtin_amdgcn_s_waitcnt(0);  // drain LDS writes (wave-local scratch)
        // run-merged per-wave pool: batch ids wave-uniform via readlane,
        // partial sums straight to global atomics.
        int curB = -1;
        float accv = 0.f;
#pragma unroll
        for (int r = 0; r < 16; ++r) {
            const int b = __builtin_amdgcn_readlane(bb, r);  // wave-uniform
            const float v = oT[r * 64 + j];
            if (b != curB) {
                if (curB >= 0) atomicAdd(&pooled[curB * 64 + j], accv);
                curB = b;
                accv = v;
            } else {
                accv += v;
            }
        }
        atomicAdd(&pooled[curB * 64 + j], accv);
    }
}

// ---------------------------------------------------------------- classifier
__global__ __launch_bounds__(64) void classifier_kernel(const float* __restrict__ pooled,
                                                        const int* __restrict__ gstart,
                                                        const float* __restrict__ wc,
                                                        const float* __restrict__ bc,
                                                        float* __restrict__ out) {
    const int g = blockIdx.x;
    const int j = threadIdx.x;
    const float c = fmaxf((float)(gstart[g + 1] - gstart[g]), 1.f);
    const float mean = pooled[g * 64 + j] / c;
#pragma unroll
    for (int cc = 0; cc < N_CLS; ++cc) {
        float p = mean * wc[j * N_CLS + cc];
#pragma unroll
        for (int off = 32; off > 0; off >>= 1) p += __shfl_down(p, off, 64);
        if (j == 0) out[g * N_CLS + cc] = p + bc[cc];
    }
}

// ---------------------------------------------------------------- launch

extern "C" void kernel_launch(void* const* d_in, const int* in_sizes, int n_in,
                              void* d_out, int out_size, void* d_ws, size_t ws_size,
                              hipStream_t stream) {
    const float* x   = (const float*)d_in[0];
    const int*   ei  = (const int*)d_in[1];
    const int* batch = (const int*)d_in[2];
    const float* w0a = (const float*)d_in[3];
    const float* b0a = (const float*)d_in[4];
    const float* g0  = (const float*)d_in[5];
    const float* be0 = (const float*)d_in[6];
    const float* m0  = (const float*)d_in[7];
    const float* v0  = (const float*)d_in[8];
    const float* w0b = (const float*)d_in[9];
    const float* b0b = (const float*)d_in[10];
    const float* w1a = (const float*)d_in[11];
    const float* b1a = (const float*)d_in[12];
    const float* g1  = (const float*)d_in[13];
    const float* be1 = (const float*)d_in[14];
    const float* m1  = (const float*)d_in[15];
    const float* v1  = (const float*)d_in[16];
    const float* w1b = (const float*)d_in[17];
    const float* b1b = (const float*)d_in[18];
    const float* wc  = (const float*)d_in[19];
    const float* bc  = (const float*)d_in[20];
    float* out = (float*)d_out;

    const int* srcI = ei;
    const int* dstI = ei + N_EDGES;

    // workspace layout, offsets in 4-byte units
    int* ws = (int*)d_ws;
    int*      deg       = ws;                              // 100000
    int*      novf      = ws + 100000;                     // 1 (inside zeroed range)
    float*    pooled    = (float*)(ws + 100404);           // 32768
    int2*     ovf       = (int2*)(ws + 133172);            // 50000 pairs (was rowptr)
    int*      slots     = ws + 233176;                     // 2,000,000 = 100000*20
    _Float16* xh        = (_Float16*)(ws + 2233176);       // 6400000 halves
    _Float16* h1        = (_Float16*)(ws + 5433176);       // 6400000 halves
    float*    b1p0      = (float*)(ws + 8633176);          // 64
    float*    b1p1      = (float*)(ws + 8633240);          // 64
    int*      gstart    = ws + 8633304;                    // 513
    _Float16* wHi       = (_Float16*)(ws + 8633820);       // 16384 halves
    _Float16* wLo       = (_Float16*)(ws + 8642012);       // 16384 halves

    (void)hipMemsetAsync((void*)deg, 0, 133172 * sizeof(int), stream);

    // prep: convert + adjacency build (slots/overflow) + gstart + W pack
    prep_kernel<<<6250, 256, 0, stream>>>(x, xh, batch, srcI, dstI,
                                          deg, slots, novf, ovf,
                                          w0a, b0a, g0, be0, m0, v0, w0b,
                                          w1a, b1a, g1, be1, m1, v1, w1b,
                                          gstart, wHi, wLo, b1p0, b1p1);

    // conv0: h1 = relu(mlp0(x + gather(x)))   [fp16 features]
    conv_mfma<0><<<NTILES2, 128, 0, stream>>>(xh, deg, slots, novf, ovf,
                                              wHi, wLo, wHi + 4096, wLo + 4096,
                                              b1p0, b0b, h1, nullptr, nullptr);

    // conv1: pooled += mlp1(h1 + gather(h1))
    conv_mfma<1><<<NTILES2, 128, 0, stream>>>(h1, deg, slots, novf, ovf,
                                              wHi + 8192, wLo + 8192, wHi + 12288, wLo + 12288,
                                              b1p1, b1b, nullptr, batch, pooled);

    classifier_kernel<<<N_GRAPHS, 64, 0, stream>>>(pooled, gstart, wc, bc, out);
}